// Round 9
// baseline (1105.709 us; speedup 1.0000x reference)
//
#include <hip/hip_runtime.h>
#include <hip/hip_bf16.h>
#include <math.h>

// Problem constants
#define N_ROUTES 7
#define PC_DIM   512
#define MC_DIM   128
#define KCLS     25
#define BATCH    4096

#define ROW_IN   (N_ROUTES * PC_DIM)          // 3584 elems per batch row of pose
#define JDIM     (KCLS * MC_DIM)              // 3200 vote cols per route
#define VOTE_B   (N_ROUTES * JDIM)            // 22400 vote elems per batch elem

typedef __attribute__((ext_vector_type(8))) _Float16 half8;
typedef __attribute__((ext_vector_type(4))) float f32x4;

__device__ inline ushort f2h(float f) {
    _Float16 h = (_Float16)f;
    return __builtin_bit_cast(ushort, h);
}

__device__ inline float2 h2f2(uint u) {
    union { uint x; _Float16 h[2]; } c; c.x = u;
    return make_float2((float)c.h[0], (float)c.h[1]);
}

__device__ inline void load_lds16(const void* g, void* l) {
    __builtin_amdgcn_global_load_lds(
        (const __attribute__((address_space(1))) void*)g,
        (__attribute__((address_space(3))) void*)l, 16, 0, 0);
}

// ---------------- conversion kernels (r12-verified forms) ----------------
__global__ __launch_bounds__(256) void conv_pose(const float* __restrict__ p,
                                                 ushort* __restrict__ pb, int n8) {
    int i = blockIdx.x * 256 + threadIdx.x;
    if (i >= n8) return;
    const float4* s = (const float4*)p + (size_t)i * 2;
    float4 a = s[0], b = s[1];
    ushort t[8];
    t[0]=f2h(a.x); t[1]=f2h(a.y); t[2]=f2h(a.z); t[3]=f2h(a.w);
    t[4]=f2h(b.x); t[5]=f2h(b.y); t[6]=f2h(b.z); t[7]=f2h(b.w);
    *(uint4*)(pb + (size_t)i * 8) = *(uint4*)t;
}

__global__ __launch_bounds__(256) void conv_w(const float* __restrict__ w,
                                              ushort* __restrict__ wt) {
    __shared__ float t[32][65];
    const int j0 = blockIdx.x * 32, d0 = blockIdx.y * 64, r = blockIdx.z;
    const int jc = threadIdx.x & 31, dr0 = threadIdx.x >> 5;   // 8 d-rows/pass
    const float* wp = w + (size_t)r * PC_DIM * JDIM;
#pragma unroll
    for (int i = 0; i < 8; i++)
        t[jc][dr0 + i * 8] = wp[(size_t)(d0 + dr0 + i * 8) * JDIM + j0 + jc];
    __syncthreads();
    const int jr = threadIdx.x >> 3, dc = (threadIdx.x & 7) * 8;
    ushort o[8];
#pragma unroll
    for (int k = 0; k < 8; k++) o[k] = f2h(t[jr][dc + k]);
    ushort* op = wt + (size_t)r * JDIM * PC_DIM;
    *(uint4*)(op + (size_t)(j0 + jr) * PC_DIM + d0 + dc) = *(uint4*)o;
}

// ---------------- Combined GEMM + routing kernel ----------------
// r15: pipeline the two big kernels. Blocks < nG: r12's verified GEMM body
// (256x128 tile, 4 waves 2Mx2N, BK=32, 3-deep rotation, counted vmcnt(6),
// unpinned inner loop) on waves 0-3; waves 4-6 idle through exactly
// GEMM_BARRIERS matched s_barriers. Blocks >= nG: r12's verified 1-elem
// 448-thread routing body. Dispatch plan (full batch):
//   D0: GEMM rows 0..2047            (grid 1400)
//   D1: GEMM rows 2048..4095 || routing rows 0..2047   (grid 3448; disjoint
//       vote regions -> no race; capacity merged instead of serialized)
//   D2: routing rows 2048..4095      (grid 2048)
// D0/D2 expose pure per-half durations of each kernel in the top-5 for the
// first time. LDS 74.5KB/block -> 2 blocks/CU of any mix; launch_bounds(448,4)
// caps VGPR<=128 to keep 14 waves/CU resident.

#define BAR() do { __builtin_amdgcn_sched_barrier(0); \
                   __builtin_amdgcn_s_barrier(); \
                   __builtin_amdgcn_sched_barrier(0); } while (0)
#define WAIT_VM(n) do { asm volatile("s_waitcnt vmcnt(" #n ")" ::: "memory"); } while (0)
#define GEMM_BARRIERS 17   // 1 prologue + 16 K-tiles; epilogue barrier-free

__global__ __launch_bounds__(448, 4) void gemm_route(
        const ushort* __restrict__ poseb,  // [4096][3584] fp16 (absolute rows)
        const ushort* __restrict__ wt,     // [7][3200][512] fp16
        ushort* __restrict__ vote,         // vote rows, row 0 == absolute vRow0
        int nG, int gRow0, int gRows, int vRow0,
        const float* __restrict__ act,
        const float* __restrict__ gamma,
        const float* __restrict__ beta,
        const float* __restrict__ emb,
        const float* __restrict__ bias,
        float* __restrict__ out_logits,
        float* __restrict__ out_act,
        float* __restrict__ out_coef,
        int rRow0) {
    __shared__ __align__(16) char smem[73728];   // GEMM: 3 bufs x (A 16KB | B 8KB)
    __shared__ float coef_s[N_ROUTES * KCLS];
    __shared__ float act_s[8];

    if ((int)blockIdx.x < nG) {
        // ---------------- GEMM role ----------------
        const int tid = threadIdx.x;
        if (tid >= 256) {                  // waves 4-6: match barrier count, exit
            for (int i = 0; i < GEMM_BARRIERS; i++) __builtin_amdgcn_s_barrier();
            return;
        }
        int route, rowTile, jTile;
        {
            const int blk = blockIdx.x;
            if (nG == 1400 && gRows == 2048) {   // 8 rowTiles x 7 x 25, XCD-local B
                const int x = blk & 7;           // XCD id (perf heuristic only)
                const int g = blk >> 3;          // 0..174
                const int q = g / 25;            // 0..6
                jTile = g - q * 25;
                const int p = x * 7 + q;         // 0..55 = route*8 + rowTileLocal
                route = p >> 3;
                rowTile = (p & 7) + (gRow0 >> 8);
            } else {
                const int rtl = blk / 175;
                const int rem = blk - rtl * 175;
                route = rem / 25;
                jTile = rem - route * 25;
                rowTile = rtl + (gRow0 >> 8);
            }
        }
        const int b0 = rowTile * 256;
        const int j0 = jTile * 128;
        const int lastRow = gRow0 + gRows - 1;

        const int l = tid & 63, w = tid >> 6;
        const int wm = w >> 1, wn = w & 1;     // 2 M-waves x 2 N-waves
        const int lm = l & 15, q4 = l >> 4;
        const int xr = (l >> 1) & 3;           // == ((row>>1)&3) for row = 16k + lm

        const ushort* Aptr = poseb + (size_t)route * PC_DIM;
        const ushort* Bptr = wt + (size_t)route * JDIM * PC_DIM;

        uint aof[4], bof[2];
        {
#pragma unroll
            for (int i = 0; i < 4; i++) {
                const int f = tid + i * 256;
                const int row = f >> 2, c = f & 3;
                const int qg = c ^ ((row >> 1) & 3);
                int ga = b0 + row; if (ga > lastRow) ga = lastRow;
                aof[i] = (uint)ga * ROW_IN + qg * 8;
            }
#pragma unroll
            for (int i = 0; i < 2; i++) {
                const int f = tid + i * 256;
                const int row = f >> 2, c = f & 3;
                const int qg = c ^ ((row >> 1) & 3);
                bof[i] = (uint)(j0 + row) * PC_DIM + qg * 8;   // j0+row <= 3199
            }
        }

        const int aBase = ((wm * 128 + lm) * 4 + (q4 ^ xr)) * 16;            // + mt*1024
        const int bBase = 16384 + ((wn * 64 + lm) * 4 + (q4 ^ xr)) * 16;     // + nt*1024

        f32x4 acc[8][4] = {};

#define STAGE(kt) do { \
        char* d_ = smem + (((kt) % 3) * 24576); \
        load_lds16(Aptr + aof[0] + (kt) * 32, d_ + (size_t)tid * 16); \
        load_lds16(Aptr + aof[1] + (kt) * 32, d_ + (size_t)(tid + 256) * 16); \
        load_lds16(Aptr + aof[2] + (kt) * 32, d_ + (size_t)(tid + 512) * 16); \
        load_lds16(Aptr + aof[3] + (kt) * 32, d_ + (size_t)(tid + 768) * 16); \
        load_lds16(Bptr + bof[0] + (kt) * 32, d_ + 16384 + (size_t)tid * 16); \
        load_lds16(Bptr + bof[1] + (kt) * 32, d_ + 16384 + (size_t)(tid + 256) * 16); \
    } while (0)

        STAGE(0); STAGE(1);
        WAIT_VM(6);
        BAR();                               // barrier #1

#pragma unroll
        for (int t = 0; t < 16; ++t) {       // barriers #2..#17
            if (t < 14) STAGE(t + 2);
            const char* bp_ = smem + ((t % 3) * 24576);
            half8 af[8], bf[4];
#pragma unroll
            for (int nt = 0; nt < 4; nt++)
                bf[nt] = *(const half8*)(bp_ + bBase + nt * 1024);
#pragma unroll
            for (int mt = 0; mt < 8; mt++)
                af[mt] = *(const half8*)(bp_ + aBase + mt * 1024);
            // Unpinned: compiler emits counted lgkmcnt interleave (r12 lesson).
#pragma unroll
            for (int mt = 0; mt < 8; mt++)
#pragma unroll
                for (int nt = 0; nt < 4; nt++)
                    acc[mt][nt] = __builtin_amdgcn_mfma_f32_16x16x32_f16(
                        af[mt], bf[nt], acc[mt][nt], 0, 0, 0);
            if (t < 14)       WAIT_VM(6);
            else if (t == 14) WAIT_VM(0);
            BAR();
        }

        // Epilogue: per-wave LDS transpose, double-region, barrier-free.
        const int erow = l >> 2, ec0 = (l & 3) * 16;
#pragma unroll
        for (int mt = 0; mt < 8; mt++) {
            float* ep = (float*)smem + w * 1088 + (mt & 1) * 4352;
#pragma unroll
            for (int nt = 0; nt < 4; nt++)
#pragma unroll
                for (int i = 0; i < 4; i++)
                    ep[(q4 * 4 + i) * 68 + nt * 16 + lm] = acc[mt][nt][i];
            asm volatile("s_waitcnt lgkmcnt(0)" ::: "memory");
            const int grow = b0 + wm * 128 + mt * 16 + erow;
            if (grow <= lastRow) {
                ushort t16[16];
#pragma unroll
                for (int t8 = 0; t8 < 4; t8++) {
                    float4 v = *(float4*)&ep[erow * 68 + ec0 + t8 * 4];
                    t16[t8*4+0]=f2h(v.x); t16[t8*4+1]=f2h(v.y);
                    t16[t8*4+2]=f2h(v.z); t16[t8*4+3]=f2h(v.w);
                }
                ushort* dst = vote + (size_t)(grow - vRow0) * VOTE_B
                                   + route * JDIM + j0 + wn * 64 + ec0;
                ((uint4*)dst)[0] = ((uint4*)t16)[0];
                ((uint4*)dst)[1] = ((uint4*)t16)[1];
            }
        }
#undef STAGE
        return;
    }

    // ---------------- routing role (r12-verified 1-elem body) ----------------
    const int b = rRow0 + ((int)blockIdx.x - nG);
    const ushort* vote16 = vote + (size_t)(b - vRow0) * VOTE_B;

    const int tid = threadIdx.x, l = tid & 63, wv = tid >> 6;   // 7 waves
    const int sub = l & 15, mg = l >> 4;
    const int m = wv + 7 * mg;                // 0..27
    const bool mv = (m < KCLS);

    if (tid < N_ROUTES) {
        float a = act[(size_t)b * N_ROUTES + tid];
        act_s[tid] = a;
        out_act[(size_t)b * N_ROUTES + tid] = a;
    }

    float vf[N_ROUTES][8];
    if (mv) {
        const uint4* vb = (const uint4*)vote16;        // n*400 + m*16 + sub
#pragma unroll
        for (int n = 0; n < N_ROUTES; n++) {
            uint4 q = vb[n * 400 + m * 16 + sub];
            float2 f0 = h2f2(q.x), f1 = h2f2(q.y), f2 = h2f2(q.z), f3 = h2f2(q.w);
            vf[n][0] = f0.x; vf[n][1] = f0.y; vf[n][2] = f1.x; vf[n][3] = f1.y;
            vf[n][4] = f2.x; vf[n][5] = f2.y; vf[n][6] = f3.x; vf[n][7] = f3.y;
        }
    } else {
#pragma unroll
        for (int n = 0; n < N_ROUTES; n++)
#pragma unroll
            for (int j = 0; j < 8; j++) vf[n][j] = 0.f;
    }
    const int mc = mv ? m : 24;

    float g[8], be[8];
    *(float4*)(g)      = *(const float4*)(gamma + 8 * sub);
    *(float4*)(g + 4)  = *(const float4*)(gamma + 8 * sub + 4);
    *(float4*)(be)     = *(const float4*)(beta  + 8 * sub);
    *(float4*)(be + 4) = *(const float4*)(beta  + 8 * sub + 4);
    __syncthreads();   // act_s ready

    const float scale = 0.088388347648318447f;    // 1/sqrt(128)
    float pose[8];

    auto update = [&](bool first) {
        float r[8];
#pragma unroll
        for (int j = 0; j < 8; j++) r[j] = 0.f;
#pragma unroll
        for (int n = 0; n < N_ROUTES; n++) {
            float c = first ? (act_s[n] * 0.04f) : (coef_s[n * KCLS + mc] * act_s[n]);
#pragma unroll
            for (int j = 0; j < 8; j++) r[j] += c * vf[n][j];
        }
        float S = 0.f, Q = 0.f;
#pragma unroll
        for (int j = 0; j < 8; j++) { S += r[j]; Q += r[j] * r[j]; }
#pragma unroll
        for (int o = 8; o; o >>= 1) {
            S += __shfl_xor(S, o);
            Q += __shfl_xor(Q, o);
        }
        float mean = S * 0.0078125f;
        float var  = Q * 0.0078125f - mean * mean;
        float rs   = rsqrtf(var + 1e-5f);
#pragma unroll
        for (int j = 0; j < 8; j++) pose[j] = (r[j] - mean) * rs * g[j] + be[j];
    };

    update(true);
    __syncthreads();

    const int sgrp = tid >> 5, slane = tid & 31;   // 14 x 32-lane groups

    for (int it = 1; it < 3; it++) {
        float d[N_ROUTES];
#pragma unroll
        for (int n = 0; n < N_ROUTES; n++) {
            float t = 0.f;
#pragma unroll
            for (int j = 0; j < 8; j++) t += vf[n][j] * pose[j];
            d[n] = t;
        }
#pragma unroll
        for (int o = 8; o; o >>= 1)
#pragma unroll
            for (int n = 0; n < N_ROUTES; n++) d[n] += __shfl_xor(d[n], o);
        if (sub == 0 && mv) {
#pragma unroll
            for (int n = 0; n < N_ROUTES; n++) coef_s[n * KCLS + m] = d[n] * scale;
        }
        __syncthreads();
        if (sgrp < N_ROUTES) {
            float c = (slane < KCLS) ? coef_s[sgrp * KCLS + slane] : -1e30f;
            float mx = c;
#pragma unroll
            for (int o = 16; o; o >>= 1) mx = fmaxf(mx, __shfl_xor(mx, o, 32));
            float e = (slane < KCLS) ? expf(c - mx) : 0.f;
            float s = e;
#pragma unroll
            for (int o = 16; o; o >>= 1) s += __shfl_xor(s, o, 32);
            if (slane < KCLS) coef_s[sgrp * KCLS + slane] = e / s;
        }
        __syncthreads();
        update(false);
        if (it == 1) __syncthreads();
    }

    float e[8];
    *(float4*)(e)     = *(const float4*)(emb + mc * MC_DIM + 8 * sub);
    *(float4*)(e + 4) = *(const float4*)(emb + mc * MC_DIM + 8 * sub + 4);
    float dd = 0.f;
#pragma unroll
    for (int j = 0; j < 8; j++) dd += pose[j] * e[j];
#pragma unroll
    for (int o = 8; o; o >>= 1) dd += __shfl_xor(dd, o);
    if (sub == 0 && mv) out_logits[(size_t)b * KCLS + m] = dd + bias[m];

    if (tid < N_ROUTES * KCLS)
        out_coef[(size_t)b * (N_ROUTES * KCLS) + tid] = coef_s[tid];
}

// ---------------- launch ----------------
extern "C" void kernel_launch(void* const* d_in, const int* in_sizes, int n_in,
                              void* d_out, int out_size, void* d_ws, size_t ws_size,
                              hipStream_t stream) {
    const float* pose  = (const float*)d_in[0];
    const float* act   = (const float*)d_in[1];
    const float* w     = (const float*)d_in[2];
    const float* gamma = (const float*)d_in[3];
    const float* beta  = (const float*)d_in[4];
    const float* emb   = (const float*)d_in[5];
    const float* bias  = (const float*)d_in[6];

    float* out        = (float*)d_out;
    float* out_logits = out;
    float* out_act    = out + BATCH * KCLS;
    float* out_coef   = out + BATCH * KCLS + BATCH * N_ROUTES;

    const size_t wt_bytes    = (size_t)N_ROUTES * JDIM * PC_DIM * 2;
    const size_t poseb_bytes = (size_t)BATCH * ROW_IN * 2;
    ushort* wt    = (ushort*)d_ws;
    ushort* poseb = (ushort*)((char*)d_ws + wt_bytes);
    ushort* voteh = (ushort*)((char*)d_ws + wt_bytes + poseb_bytes);

    size_t rem = ws_size > wt_bytes + poseb_bytes ? ws_size - wt_bytes - poseb_bytes : 0;
    size_t cap = rem / ((size_t)VOTE_B * 2);

    conv_w<<<dim3(JDIM / 32, PC_DIM / 64, N_ROUTES), 256, 0, stream>>>(w, wt);
    const int n8 = BATCH * ROW_IN / 8;
    conv_pose<<<(n8 + 255) / 256, 256, 0, stream>>>(pose, poseb, n8);

    if (cap >= (size_t)BATCH) {
        const int H = BATCH / 2;   // 2048
        // D0: GEMM rows 0..H-1
        gemm_route<<<1400, 448, 0, stream>>>(
            poseb, wt, voteh, 1400, 0, H, 0,
            act, gamma, beta, emb, bias, out_logits, out_act, out_coef, 0);
        // D1: GEMM rows H..2H-1  ||  routing rows 0..H-1
        gemm_route<<<1400 + H, 448, 0, stream>>>(
            poseb, wt, voteh, 1400, H, H, 0,
            act, gamma, beta, emb, bias, out_logits, out_act, out_coef, 0);
        // D2: routing rows H..2H-1
        gemm_route<<<H, 448, 0, stream>>>(
            poseb, wt, voteh, 0, 0, 0, 0,
            act, gamma, beta, emb, bias, out_logits, out_act, out_coef, H);
    } else {
        // Fallback: serial per-chunk (chunk-local vote buffer), same kernel.
        int chunk;
        if (cap >= 256) chunk = (int)(cap & ~(size_t)255);
        else            chunk = (int)(cap > 0 ? cap : 1);
        for (int b0 = 0; b0 < BATCH; b0 += chunk) {
            int rows = BATCH - b0 < chunk ? BATCH - b0 : chunk;
            int nRT = (rows + 255) / 256;
            gemm_route<<<nRT * 175, 448, 0, stream>>>(
                poseb, wt, voteh, nRT * 175, b0, rows, b0,
                act, gamma, beta, emb, bias, out_logits, out_act, out_coef, 0);
            gemm_route<<<rows, 448, 0, stream>>>(
                poseb, wt, voteh, 0, 0, 0, b0,
                act, gamma, beta, emb, bias, out_logits, out_act, out_coef, b0);
        }
    }
}

// Round 10
// 350.260 us; speedup vs baseline: 3.1568x; 3.1568x over previous
//
#include <hip/hip_runtime.h>
#include <hip/hip_bf16.h>
#include <math.h>

// Problem constants
#define N_ROUTES 7
#define PC_DIM   512
#define MC_DIM   128
#define KCLS     25
#define BATCH    4096

#define ROW_IN   (N_ROUTES * PC_DIM)          // 3584 elems per batch row of pose
#define JDIM     (KCLS * MC_DIM)              // 3200 vote cols per route
#define VOTE_B   (N_ROUTES * JDIM)            // 22400 vote elems per batch elem

typedef __attribute__((ext_vector_type(8))) _Float16 half8;
typedef __attribute__((ext_vector_type(4))) float f32x4;

__device__ inline ushort f2h(float f) {
    _Float16 h = (_Float16)f;
    return __builtin_bit_cast(ushort, h);
}

__device__ inline float2 h2f2(uint u) {
    union { uint x; _Float16 h[2]; } c; c.x = u;
    return make_float2((float)c.h[0], (float)c.h[1]);
}

__device__ inline void load_lds16(const void* g, void* l) {
    __builtin_amdgcn_global_load_lds(
        (const __attribute__((address_space(1))) void*)g,
        (__attribute__((address_space(3))) void*)l, 16, 0, 0);
}

// ---------------- conversion kernels (r12-verified forms) ----------------
__global__ __launch_bounds__(256) void conv_pose(const float* __restrict__ p,
                                                 ushort* __restrict__ pb, int n8) {
    int i = blockIdx.x * 256 + threadIdx.x;
    if (i >= n8) return;
    const float4* s = (const float4*)p + (size_t)i * 2;
    float4 a = s[0], b = s[1];
    ushort t[8];
    t[0]=f2h(a.x); t[1]=f2h(a.y); t[2]=f2h(a.z); t[3]=f2h(a.w);
    t[4]=f2h(b.x); t[5]=f2h(b.y); t[6]=f2h(b.z); t[7]=f2h(b.w);
    *(uint4*)(pb + (size_t)i * 8) = *(uint4*)t;
}

__global__ __launch_bounds__(256) void conv_w(const float* __restrict__ w,
                                              ushort* __restrict__ wt) {
    __shared__ float t[32][65];
    const int j0 = blockIdx.x * 32, d0 = blockIdx.y * 64, r = blockIdx.z;
    const int jc = threadIdx.x & 31, dr0 = threadIdx.x >> 5;   // 8 d-rows/pass
    const float* wp = w + (size_t)r * PC_DIM * JDIM;
#pragma unroll
    for (int i = 0; i < 8; i++)
        t[jc][dr0 + i * 8] = wp[(size_t)(d0 + dr0 + i * 8) * JDIM + j0 + jc];
    __syncthreads();
    const int jr = threadIdx.x >> 3, dc = (threadIdx.x & 7) * 8;
    ushort o[8];
#pragma unroll
    for (int k = 0; k < 8; k++) o[k] = f2h(t[jr][dc + k]);
    ushort* op = wt + (size_t)r * JDIM * PC_DIM;
    *(uint4*)(op + (size_t)(j0 + jr) * PC_DIM + d0 + dc) = *(uint4*)o;
}

// ---------------- Kernel 1: MFMA vote GEMM (fp16 in, fp16 out) ----------------
// r16 = r12 body (verified 122us full-batch, MfmaUtil 33.5%), launched as FOUR
// quarter-dispatches (1024 rows, grid 700) so the routing kernel becomes the
// largest single dispatch and finally surfaces in the rocprof top-5 with
// counters (measurement round; r15's mixed-kernel attempt spilled to scratch
// via launch_bounds(448,4) -- VGPR 64 -- and is abandoned).
// Grid 700: bijective XCD swizzle (m204 form; 700 = 8*87+4), jTile-inner ->
// per-XCD B working set ~ sequential route panels (L2-resident).

#define BAR() do { __builtin_amdgcn_sched_barrier(0); \
                   __builtin_amdgcn_s_barrier(); \
                   __builtin_amdgcn_sched_barrier(0); } while (0)
#define WAIT_VM(n) do { asm volatile("s_waitcnt vmcnt(" #n ")" ::: "memory"); } while (0)

__global__ __launch_bounds__(256, 2) void vote_gemm_mfma(
        const ushort* __restrict__ poseb,  // [rows][3584] fp16 (quarter-offset)
        const ushort* __restrict__ wt,     // [7][3200][512] fp16
        ushort* __restrict__ vote,         // [rows][7][3200] fp16 (quarter-local)
        int rows) {
    __shared__ __align__(16) char smem[73728];   // 3 bufs x (A 16KB | B 8KB)

    int route, rowTile, jTile;
    {
        const int blk = blockIdx.x;
        if (gridDim.x == 700) {            // quarter batch: 4 rowTiles x 7 x 25
            // Bijective XCD swizzle: 700 = 8*87+4 (XCDs 0-3 get 88, 4-7 get 87).
            const int xcd = blk & 7;
            const int k = blk >> 3;
            const int wgid = (xcd < 4 ? xcd * 88 : 352 + (xcd - 4) * 87) + k;
            rowTile = wgid / 175;
            const int rem = wgid - rowTile * 175;
            route = rem / 25;
            jTile = rem - route * 25;
        } else if (gridDim.x == 2800) {    // full batch (r12 map, kept)
            const int x = blk & 7;
            const int g = blk >> 3;
            const int q = g / 25;
            jTile = g - q * 25;
            const int p = x * 14 + q;
            route = p >> 4;
            rowTile = p & 15;
        } else {
            rowTile = blk / 175;
            const int rem = blk - rowTile * 175;
            route = rem / 25;
            jTile = rem - route * 25;
        }
    }
    const int b0 = rowTile * 256;
    const int j0 = jTile * 128;

    const int tid = threadIdx.x;
    const int l = tid & 63, w = tid >> 6;
    const int wm = w >> 1, wn = w & 1;     // 2 M-waves x 2 N-waves
    const int lm = l & 15, q4 = l >> 4;
    const int xr = (l >> 1) & 3;           // == ((row>>1)&3) for row = 16k + lm

    const ushort* Aptr = poseb + (size_t)route * PC_DIM;
    const ushort* Bptr = wt + (size_t)route * JDIM * PC_DIM;

    // Staging source offsets (elements). A: 1024 chunks of 8 fp16 (256 rows x 4);
    // B: 512 chunks (128 rows x 4). chunk f: row = f>>2, c = f&3, pre-swizzled
    // source col-group qg = c ^ ((row>>1)&3).
    uint aof[4], bof[2];
    {
#pragma unroll
        for (int i = 0; i < 4; i++) {
            const int f = tid + i * 256;
            const int row = f >> 2, c = f & 3;
            const int qg = c ^ ((row >> 1) & 3);
            int ga = b0 + row; if (ga >= rows) ga = rows - 1;
            aof[i] = (uint)ga * ROW_IN + qg * 8;
        }
#pragma unroll
        for (int i = 0; i < 2; i++) {
            const int f = tid + i * 256;
            const int row = f >> 2, c = f & 3;
            const int qg = c ^ ((row >> 1) & 3);
            bof[i] = (uint)(j0 + row) * PC_DIM + qg * 8;   // j0+row <= 3199 always
        }
    }

    // LDS byte offsets of this lane's fragments (swizzled read side).
    const int aBase = ((wm * 128 + lm) * 4 + (q4 ^ xr)) * 16;            // + mt*1024
    const int bBase = 16384 + ((wn * 64 + lm) * 4 + (q4 ^ xr)) * 16;     // + nt*1024

    f32x4 acc[8][4] = {};

#define STAGE(kt) do { \
        char* d_ = smem + (((kt) % 3) * 24576); \
        load_lds16(Aptr + aof[0] + (kt) * 32, d_ + (size_t)tid * 16); \
        load_lds16(Aptr + aof[1] + (kt) * 32, d_ + (size_t)(tid + 256) * 16); \
        load_lds16(Aptr + aof[2] + (kt) * 32, d_ + (size_t)(tid + 512) * 16); \
        load_lds16(Aptr + aof[3] + (kt) * 32, d_ + (size_t)(tid + 768) * 16); \
        load_lds16(Bptr + bof[0] + (kt) * 32, d_ + 16384 + (size_t)tid * 16); \
        load_lds16(Bptr + bof[1] + (kt) * 32, d_ + 16384 + (size_t)(tid + 256) * 16); \
    } while (0)

    // Prologue: tiles 0,1 staged (12 loads/thread); wait tile0 (leave 6).
    STAGE(0); STAGE(1);
    WAIT_VM(6);
    BAR();

#pragma unroll
    for (int t = 0; t < 16; ++t) {
        if (t < 14) STAGE(t + 2);          // issue-early: loads in flight across tile
        const char* bp_ = smem + ((t % 3) * 24576);
        half8 af[8], bf[4];
#pragma unroll
        for (int nt = 0; nt < 4; nt++)
            bf[nt] = *(const half8*)(bp_ + bBase + nt * 1024);
#pragma unroll
        for (int mt = 0; mt < 8; mt++)
            af[mt] = *(const half8*)(bp_ + aBase + mt * 1024);
        // Unpinned inner phase (r12 lesson: compiler emits counted lgkmcnt).
#pragma unroll
        for (int mt = 0; mt < 8; mt++)
#pragma unroll
            for (int nt = 0; nt < 4; nt++)
                acc[mt][nt] = __builtin_amdgcn_mfma_f32_16x16x32_f16(
                    af[mt], bf[nt], acc[mt][nt], 0, 0, 0);
        if (t < 14)       WAIT_VM(6);      // tile t+1 landed; t+2 still in flight
        else if (t == 14) WAIT_VM(0);      // drain: tile 15 landed
        BAR();                             // also protects epilogue smem reuse (t=15)
    }

    // Epilogue: per-wave LDS transpose, double-region (no trailing wait).
    const int erow = l >> 2, ec0 = (l & 3) * 16;
#pragma unroll
    for (int mt = 0; mt < 8; mt++) {
        float* ep = (float*)smem + w * 1088 + (mt & 1) * 4352;
#pragma unroll
        for (int nt = 0; nt < 4; nt++)
#pragma unroll
            for (int i = 0; i < 4; i++)
                ep[(q4 * 4 + i) * 68 + nt * 16 + lm] = acc[mt][nt][i];
        asm volatile("s_waitcnt lgkmcnt(0)" ::: "memory");
        const int grow = b0 + wm * 128 + mt * 16 + erow;
        if (grow < rows) {
            ushort t16[16];
#pragma unroll
            for (int t8 = 0; t8 < 4; t8++) {
                float4 v = *(float4*)&ep[erow * 68 + ec0 + t8 * 4];
                t16[t8*4+0]=f2h(v.x); t16[t8*4+1]=f2h(v.y);
                t16[t8*4+2]=f2h(v.z); t16[t8*4+3]=f2h(v.w);
            }
            ushort* dst = vote + (size_t)grow * VOTE_B + route * JDIM + j0 + wn * 64 + ec0;
            ((uint4*)dst)[0] = ((uint4*)t16)[0];
            ((uint4*)dst)[1] = ((uint4*)t16)[1];
        }
    }
}

// ---------------- Kernel 2: fused routing (r12-verified, byte-identical) ----------------
// Block = one batch elem, 448 threads (7 waves). Lane decomposition:
//   sub = l&15 -> v-dims [8*sub, 8*sub+8);  mg = l>>4;  m = wv + 7*mg (28 slots, 25 valid).
// Votes unpacked ONCE to 56 fp32 regs. Reductions: 4-step shfl over 16 lanes.
__global__ __launch_bounds__(448) void routing_kernel(
        const ushort* __restrict__ vote16,  // [chunk][7][25][128] fp16
        const float* __restrict__ act,      // (pre-offset)
        const float* __restrict__ gamma,
        const float* __restrict__ beta,
        const float* __restrict__ emb,      // [25,128]
        const float* __restrict__ bias,     // [25]
        float* __restrict__ out_logits,
        float* __restrict__ out_act,
        float* __restrict__ out_coef) {
    const int b = blockIdx.x;
    __shared__ float coef_s[N_ROUTES * KCLS];
    __shared__ float act_s[8];

    const int tid = threadIdx.x, l = tid & 63, wv = tid >> 6;   // 7 waves
    const int sub = l & 15, mg = l >> 4;
    const int m = wv + 7 * mg;                // 0..27
    const bool mv = (m < KCLS);

    if (tid < N_ROUTES) {
        float a = act[(size_t)b * N_ROUTES + tid];
        act_s[tid] = a;
        out_act[(size_t)b * N_ROUTES + tid] = a;
    }

    // Load votes (coalesced 16B) and unpack to fp32 ONCE.
    float vf[N_ROUTES][8];
    if (mv) {
        const uint4* vb = (const uint4*)(vote16 + (size_t)b * VOTE_B);  // n*400 + m*16 + sub
#pragma unroll
        for (int n = 0; n < N_ROUTES; n++) {
            uint4 q = vb[n * 400 + m * 16 + sub];
            float2 f0 = h2f2(q.x), f1 = h2f2(q.y), f2 = h2f2(q.z), f3 = h2f2(q.w);
            vf[n][0] = f0.x; vf[n][1] = f0.y; vf[n][2] = f1.x; vf[n][3] = f1.y;
            vf[n][4] = f2.x; vf[n][5] = f2.y; vf[n][6] = f3.x; vf[n][7] = f3.y;
        }
    } else {
#pragma unroll
        for (int n = 0; n < N_ROUTES; n++)
#pragma unroll
            for (int j = 0; j < 8; j++) vf[n][j] = 0.f;
    }
    const int mc = mv ? m : 24;

    float g[8], be[8];
    *(float4*)(g)      = *(const float4*)(gamma + 8 * sub);
    *(float4*)(g + 4)  = *(const float4*)(gamma + 8 * sub + 4);
    *(float4*)(be)     = *(const float4*)(beta  + 8 * sub);
    *(float4*)(be + 4) = *(const float4*)(beta  + 8 * sub + 4);
    __syncthreads();   // act_s ready

    const float scale = 0.088388347648318447f;    // 1/sqrt(128)
    float pose[8];

    auto update = [&](bool first) {
        float r[8];
#pragma unroll
        for (int j = 0; j < 8; j++) r[j] = 0.f;
#pragma unroll
        for (int n = 0; n < N_ROUTES; n++) {
            float c = first ? (act_s[n] * 0.04f) : (coef_s[n * KCLS + mc] * act_s[n]);
#pragma unroll
            for (int j = 0; j < 8; j++) r[j] += c * vf[n][j];
        }
        float S = 0.f, Q = 0.f;
#pragma unroll
        for (int j = 0; j < 8; j++) { S += r[j]; Q += r[j] * r[j]; }
#pragma unroll
        for (int o = 8; o; o >>= 1) {
            S += __shfl_xor(S, o);
            Q += __shfl_xor(Q, o);
        }
        float mean = S * 0.0078125f;
        float var  = Q * 0.0078125f - mean * mean;
        float rs   = rsqrtf(var + 1e-5f);
#pragma unroll
        for (int j = 0; j < 8; j++) pose[j] = (r[j] - mean) * rs * g[j] + be[j];
    };

    update(true);
    __syncthreads();

    const int sgrp = tid >> 5, slane = tid & 31;   // 14 x 32-lane groups for softmax

    for (int it = 1; it < 3; it++) {
        // agreement: d[n] = <vote[n][m], pose[m]>
        float d[N_ROUTES];
#pragma unroll
        for (int n = 0; n < N_ROUTES; n++) {
            float t = 0.f;
#pragma unroll
            for (int j = 0; j < 8; j++) t += vf[n][j] * pose[j];
            d[n] = t;
        }
#pragma unroll
        for (int o = 8; o; o >>= 1)
#pragma unroll
            for (int n = 0; n < N_ROUTES; n++) d[n] += __shfl_xor(d[n], o);
        if (sub == 0 && mv) {
#pragma unroll
            for (int n = 0; n < N_ROUTES; n++) coef_s[n * KCLS + m] = d[n] * scale;
        }
        __syncthreads();
        // parallel softmax: group sgrp = route, lane slane = m
        if (sgrp < N_ROUTES) {
            float c = (slane < KCLS) ? coef_s[sgrp * KCLS + slane] : -1e30f;
            float mx = c;
#pragma unroll
            for (int o = 16; o; o >>= 1) mx = fmaxf(mx, __shfl_xor(mx, o, 32));
            float e = (slane < KCLS) ? expf(c - mx) : 0.f;
            float s = e;
#pragma unroll
            for (int o = 16; o; o >>= 1) s += __shfl_xor(s, o, 32);
            if (slane < KCLS) coef_s[sgrp * KCLS + slane] = e / s;
        }
        __syncthreads();
        update(false);
        if (it == 1) __syncthreads();   // coef_s reads done before next agree overwrites
    }

    // logits
    float e[8];
    *(float4*)(e)     = *(const float4*)(emb + mc * MC_DIM + 8 * sub);
    *(float4*)(e + 4) = *(const float4*)(emb + mc * MC_DIM + 8 * sub + 4);
    float dd = 0.f;
#pragma unroll
    for (int j = 0; j < 8; j++) dd += pose[j] * e[j];
#pragma unroll
    for (int o = 8; o; o >>= 1) dd += __shfl_xor(dd, o);
    if (sub == 0 && mv) out_logits[(size_t)b * KCLS + m] = dd + bias[m];

    if (tid < N_ROUTES * KCLS)
        out_coef[(size_t)b * (N_ROUTES * KCLS) + tid] = coef_s[tid];
}

// ---------------- launch ----------------
extern "C" void kernel_launch(void* const* d_in, const int* in_sizes, int n_in,
                              void* d_out, int out_size, void* d_ws, size_t ws_size,
                              hipStream_t stream) {
    const float* pose  = (const float*)d_in[0];
    const float* act   = (const float*)d_in[1];
    const float* w     = (const float*)d_in[2];
    const float* gamma = (const float*)d_in[3];
    const float* beta  = (const float*)d_in[4];
    const float* emb   = (const float*)d_in[5];
    const float* bias  = (const float*)d_in[6];

    float* out        = (float*)d_out;
    float* out_logits = out;
    float* out_act    = out + BATCH * KCLS;
    float* out_coef   = out + BATCH * KCLS + BATCH * N_ROUTES;

    // workspace: wt fp16 | poseb fp16 | vote fp16 (chunked)
    const size_t wt_bytes    = (size_t)N_ROUTES * JDIM * PC_DIM * 2;
    const size_t poseb_bytes = (size_t)BATCH * ROW_IN * 2;
    ushort* wt    = (ushort*)d_ws;
    ushort* poseb = (ushort*)((char*)d_ws + wt_bytes);
    ushort* voteh = (ushort*)((char*)d_ws + wt_bytes + poseb_bytes);

    size_t rem = ws_size > wt_bytes + poseb_bytes ? ws_size - wt_bytes - poseb_bytes : 0;
    size_t cap = rem / ((size_t)VOTE_B * 2);

    conv_w<<<dim3(JDIM / 32, PC_DIM / 64, N_ROUTES), 256, 0, stream>>>(w, wt);
    const int n8 = BATCH * ROW_IN / 8;
    conv_pose<<<(n8 + 255) / 256, 256, 0, stream>>>(pose, poseb, n8);

    if (cap >= (size_t)BATCH) {
        // GEMM as 4 quarter-dispatches (grid 700 each) so routing becomes the
        // largest dispatch and surfaces in the rocprof top-5 (measurement round).
        for (int qi = 0; qi < 4; qi++) {
            const int b0 = qi * 1024;
            vote_gemm_mfma<<<700, 256, 0, stream>>>(
                poseb + (size_t)b0 * ROW_IN, wt,
                voteh + (size_t)b0 * VOTE_B, 1024);
        }
        routing_kernel<<<BATCH, 448, 0, stream>>>(
            voteh, act, gamma, beta, emb, bias,
            out_logits, out_act, out_coef);
    } else {
        int chunk;
        if (cap >= 256) chunk = (int)(cap & ~(size_t)255);
        else            chunk = (int)(cap > 0 ? cap : 1);
        for (int b0 = 0; b0 < BATCH; b0 += chunk) {
            int rows = BATCH - b0 < chunk ? BATCH - b0 : chunk;
            int nRowTiles = (rows + 255) / 256;
            vote_gemm_mfma<<<nRowTiles * 175, 256, 0, stream>>>(
                poseb + (size_t)b0 * ROW_IN, wt, voteh, rows);
            routing_kernel<<<rows, 448, 0, stream>>>(
                voteh,
                act + (size_t)b0 * N_ROUTES,
                gamma, beta, emb, bias,
                out_logits + (size_t)b0 * KCLS,
                out_act    + (size_t)b0 * N_ROUTES,
                out_coef   + (size_t)b0 * N_ROUTES * KCLS);
        }
    }
}